// Round 13
// baseline (140.468 us; speedup 1.0000x reference)
//
#include <hip/hip_runtime.h>
#include <hip/hip_bf16.h>

#define FEAT 256
#define HEADS 8
#define HD 32
#define POSN 128
#define NEGN 128
#define HWN 16384
#define BN 8
#define NSLOT 512
#define S_TOT 256
#define LN_EPS 1e-5f
#define NBKT 4096
#define AFF_OFF (NSLOT*FEAT)   /* 131072 floats: new_slots first, then affinities */

typedef float f32x4 __attribute__((ext_vector_type(4)));

__device__ __forceinline__ unsigned short bf16r(float x) {
    unsigned int u = __float_as_uint(x);
    u += 0x7FFFu + ((u >> 16) & 1u);       // round to nearest even
    return (unsigned short)(u >> 16);
}
__device__ __forceinline__ float bf16f(unsigned short h) {
    return __uint_as_float((unsigned int)h << 16);
}

// ---------------- fully fused per-slot pipeline ------------------------------
// One block per slot, 512 threads. Everything is block-local:
//   A: exact top-k sampling (bucket sort over curio row, 512-thread adapted)
//   B: folded qkw[h][f] = sum_d q[hd]*kw[hd,f] into LDS
//   C: POS gather + affinities (bf16 reg cache), softmax
//   D: NEG gather interleaved with weighted-sum, partial combine
//   E: V-proj, out-proj, residual, LayerNorm
// LDS: 58KB phase union + ~11KB dedicated = ~69KB -> 2 blocks/CU.
__global__ __launch_bounds__(512) void k_fused(const float* __restrict__ curio,
                                               const int* __restrict__ mme_p,
                                               const float* __restrict__ slots,
                                               const float* __restrict__ ipw,
                                               const float* __restrict__ ipb,
                                               const int* __restrict__ batch_idx,
                                               const float* __restrict__ features,
                                               const float* __restrict__ pos_enc,
                                               const float* __restrict__ out_w,
                                               const float* __restrict__ out_b,
                                               const float* __restrict__ ln_g,
                                               const float* __restrict__ ln_b,
                                               float* __restrict__ aff_out,
                                               float* __restrict__ out)
{
    __shared__ __align__(16) char U[59392];   // phase union
    // phase A views
    unsigned int* hist = (unsigned int*)U;                    // 16384 B
    uint16_t*     offs = (uint16_t*)(U + 16384);              // 8192 B
    uint16_t*     sidx = (uint16_t*)(U + 24576);              // 32768 B
    unsigned int* ssum = (unsigned int*)(U + 57344);          // 2048 B
    // phase C/D views
    float (*affP)[8] = (float(*)[8])U;                        // 4096 B
    f32x4 (*wfp)[HEADS][64] = (f32x4(*)[HEADS][64])(U + 4096);// 32768 B
    // phase E views
    f32x4 (*wf4)[64] = (f32x4(*)[64])(U + 36864);             // 8192 B
    float* aoh  = (float*)(U + 45056);                        // 2048 B
    float* ao_l = (float*)(U + 47104);                        // 1024 B
    float* xgh  = (float*)(U + 48128);                        // 2048 B
    float* rr12 = (float*)(U + 50176);                        // 32 B (r1[4],r2[4])
    // dedicated (live across phases)
    __shared__ int   fi_l[S_TOT];        // 1KB
    __shared__ float qkwL[HEADS*FEAT];   // 8KB
    __shared__ float qkb_l[HEADS];
    __shared__ float srow[FEAT];         // 1KB
    __shared__ float qrow[FEAT];         // 1KB

    int n = blockIdx.x, t = threadIdx.x, lane = t & 63, w = t >> 6;
    const float* cm = curio + (size_t)n * HWN;
    const f32x4* cm4 = (const f32x4*)cm;
    int b = batch_idx[n];

    // ================= Phase A: sampling (512 threads) ======================
    for (int i = t; i < NBKT; i += 512) hist[i] = 0;
    __syncthreads();

    unsigned int bkA[8], bkB[8];
#pragma unroll
    for (int j = 0; j < 8; j++) {
        f32x4 v = cm4[j * 512 + t];
        int c0 = (int)(v[0] * 4096.0f); c0 = c0 < 0 ? 0 : (c0 > NBKT-1 ? NBKT-1 : c0);
        int c1 = (int)(v[1] * 4096.0f); c1 = c1 < 0 ? 0 : (c1 > NBKT-1 ? NBKT-1 : c1);
        int c2 = (int)(v[2] * 4096.0f); c2 = c2 < 0 ? 0 : (c2 > NBKT-1 ? NBKT-1 : c2);
        int c3 = (int)(v[3] * 4096.0f); c3 = c3 < 0 ? 0 : (c3 > NBKT-1 ? NBKT-1 : c3);
        bkA[j] = (unsigned int)c0 | ((unsigned int)c1 << 16);
        bkB[j] = (unsigned int)c2 | ((unsigned int)c3 << 16);
        atomicAdd(&hist[c0], 1u); atomicAdd(&hist[c1], 1u);
        atomicAdd(&hist[c2], 1u); atomicAdd(&hist[c3], 1u);
    }
    __syncthreads();

    // descending-order exclusive prefix: offs[b] = sum_{b'>b} hist[b']
    {
        unsigned int lsum = 0;
        int base = t * 8;
        for (int j = 0; j < 8; j++) lsum += hist[NBKT-1 - (base + j)];
        ssum[t] = lsum; __syncthreads();
        for (int off = 1; off < 512; off <<= 1) {
            unsigned int v = (t >= off) ? ssum[t - off] : 0u;
            __syncthreads();
            ssum[t] += v;
            __syncthreads();
        }
        unsigned int run = ssum[t] - lsum;
        for (int j = 0; j < 8; j++) {
            int bb = NBKT-1 - (base + j);
            offs[bb] = (uint16_t)run;
            run += hist[bb];
        }
    }
    __syncthreads();
    for (int i = t; i < NBKT; i += 512) hist[i] = 0;
    __syncthreads();

    // scatter from register-cached buckets
#pragma unroll
    for (int j = 0; j < 8; j++) {
        int idx0 = (j * 512 + t) * 4;
        int c0 = (int)(bkA[j] & 0xFFFFu), c1 = (int)(bkA[j] >> 16);
        int c2 = (int)(bkB[j] & 0xFFFFu), c3 = (int)(bkB[j] >> 16);
        unsigned int p0 = (unsigned int)offs[c0] + atomicAdd(&hist[c0], 1u);
        sidx[p0] = (uint16_t)(idx0 + 0);
        unsigned int p1 = (unsigned int)offs[c1] + atomicAdd(&hist[c1], 1u);
        sidx[p1] = (uint16_t)(idx0 + 1);
        unsigned int p2 = (unsigned int)offs[c2] + atomicAdd(&hist[c2], 1u);
        sidx[p2] = (uint16_t)(idx0 + 2);
        unsigned int p3 = (unsigned int)offs[c3] + atomicAdd(&hist[c3], 1u);
        sidx[p3] = (uint16_t)(idx0 + 3);
    }
    __syncthreads();

    // exact rank selection (argsort of -v, stable: value desc, idx asc)
    if (t < S_TOT) {
        int mme = mme_p[0];
        int stride = (HWN - POSN - mme) / NEGN;          // 127 for mme=0
        int r = (t < POSN) ? t : (POSN + stride * (t - POSN));
        int lo = 0, hi = NBKT - 1;
        while (lo < hi) { int mid = (lo + hi) >> 1; if ((int)offs[mid] <= r) hi = mid; else lo = mid + 1; }
        int bkt = lo;
        int start = (int)offs[bkt];
        int cnt   = (int)hist[bkt];
        int rsel  = r - start;
        int besti = sidx[start + (rsel < cnt ? rsel : 0)];
        for (int j = 0; j < cnt; j++) {
            int ij = sidx[start + j];
            float vj = cm[ij];
            int rank = 0;
            for (int j2 = 0; j2 < cnt; j2++) {
                int i2 = sidx[start + j2];
                float v2 = cm[i2];
                if (v2 > vj || (v2 == vj && i2 < ij)) rank++;
            }
            if (rank == rsel) { besti = ij; break; }
        }
        fi_l[t] = besti;
    }

    // ================= Phase B: folded qkw into LDS =========================
    __syncthreads();
    if (t < FEAT) srow[t] = slots[n * FEAT + t];
    __syncthreads();
    if (t < FEAT) {
        const float* qwrow = ipw + (size_t)t * FEAT;
        float acc = 0.f;
#pragma unroll 8
        for (int f = 0; f < FEAT; f++) acc += srow[f] * qwrow[f];
        const float scaling = 0.17677669529663687f;     // 32^-0.5
        qrow[t] = (acc + ipb[t]) * scaling;
    }
    __syncthreads();
    if (t < HEADS) {
        float s = 0.f;
        for (int d = 0; d < HD; d++) s += qrow[t*HD + d] * ipb[FEAT + t*HD + d];
        qkb_l[t] = s;
    }
    {
        const float* kw = ipw + FEAT * FEAT;
        for (int e = t; e < HEADS * FEAT; e += 512) {
            int h = e >> 8, f = e & 255;
            float s = 0.f;
#pragma unroll
            for (int d = 0; d < HD; d++) s += qrow[h*HD + d] * kw[(h*HD + d) * FEAT + f];
            qkwL[e] = s;
        }
    }
    __syncthreads();

    // per-lane qkw slices from LDS
    f32x4 qw0 = *(const f32x4*)&qkwL[0*FEAT + 4*lane];
    f32x4 qw1 = *(const f32x4*)&qkwL[1*FEAT + 4*lane];
    f32x4 qw2 = *(const f32x4*)&qkwL[2*FEAT + 4*lane];
    f32x4 qw3 = *(const f32x4*)&qkwL[3*FEAT + 4*lane];
    f32x4 qw4 = *(const f32x4*)&qkwL[4*FEAT + 4*lane];
    f32x4 qw5 = *(const f32x4*)&qkwL[5*FEAT + 4*lane];
    f32x4 qw6 = *(const f32x4*)&qkwL[6*FEAT + 4*lane];
    f32x4 qw7 = *(const f32x4*)&qkwL[7*FEAT + 4*lane];
    float qb = qkb_l[lane & 7];
    int e0 = lane & 1, e1 = (lane >> 1) & 1, e2 = (lane >> 2) & 1;

    auto dorow = [&](int p, f32x4 x, bool toLds) {
        float p0 = x[0]*qw0[0] + x[1]*qw0[1] + x[2]*qw0[2] + x[3]*qw0[3];
        float p1 = x[0]*qw1[0] + x[1]*qw1[1] + x[2]*qw1[2] + x[3]*qw1[3];
        float p2 = x[0]*qw2[0] + x[1]*qw2[1] + x[2]*qw2[2] + x[3]*qw2[3];
        float p3 = x[0]*qw3[0] + x[1]*qw3[1] + x[2]*qw3[2] + x[3]*qw3[3];
        float p4 = x[0]*qw4[0] + x[1]*qw4[1] + x[2]*qw4[2] + x[3]*qw4[3];
        float p5 = x[0]*qw5[0] + x[1]*qw5[1] + x[2]*qw5[2] + x[3]*qw5[3];
        float p6 = x[0]*qw6[0] + x[1]*qw6[1] + x[2]*qw6[2] + x[3]*qw6[3];
        float p7 = x[0]*qw7[0] + x[1]*qw7[1] + x[2]*qw7[2] + x[3]*qw7[3];
        float s0 = e0 ? p0 : p1, s1 = e0 ? p2 : p3, s2 = e0 ? p4 : p5, s3 = e0 ? p6 : p7;
        float a0 = (e0 ? p1 : p0) + __shfl_xor(s0, 1);
        float a1 = (e0 ? p3 : p2) + __shfl_xor(s1, 1);
        float a2 = (e0 ? p5 : p4) + __shfl_xor(s2, 1);
        float a3 = (e0 ? p7 : p6) + __shfl_xor(s3, 1);
        float u0 = e1 ? a0 : a1, u1 = e1 ? a2 : a3;
        float c0 = (e1 ? a1 : a0) + __shfl_xor(u0, 2);
        float c1 = (e1 ? a3 : a2) + __shfl_xor(u1, 2);
        float u2 = e2 ? c0 : c1;
        float d = (e2 ? c1 : c0) + __shfl_xor(u2, 4);
        d += __shfl_xor(d, 8);
        d += __shfl_xor(d, 16);
        d += __shfl_xor(d, 32);
        d += qb;
        if (lane < 8) {
            aff_out[(size_t)p * (NSLOT*HEADS) + n*HEADS + lane] = d;
            if (toLds) affP[p][lane] = d;
        }
    };

    auto rowaddr = [&](int s) {
        return ((size_t)fi_l[s] * BN + b) * FEAT + 4 * lane;
    };

    // ================= Phase C: POS gather + affinities =====================
    ushort4 cache[16];
    {
        size_t aA = rowaddr(w);
        size_t aB = rowaddr(w + 8);
        f32x4 fA = *(const f32x4*)(features + aA), gA = *(const f32x4*)(pos_enc + aA);
        f32x4 fB = *(const f32x4*)(features + aB), gB = *(const f32x4*)(pos_enc + aB);
#pragma unroll
        for (int i = 0; i < 16; i += 2) {
            f32x4 cf = fA, cg = gA;
            if (i + 2 < 16) {
                size_t nb = rowaddr(w + 8*(i+2));
                fA = *(const f32x4*)(features + nb); gA = *(const f32x4*)(pos_enc + nb);
            }
            { ushort4 pk; pk.x = bf16r(cf[0]); pk.y = bf16r(cf[1]);
              pk.z = bf16r(cf[2]); pk.w = bf16r(cf[3]); cache[i] = pk; }
            dorow(w + 8*i, cf + cg, true);
            f32x4 cf2 = fB, cg2 = gB;
            if (i + 3 < 16) {
                size_t nb = rowaddr(w + 8*(i+3));
                fB = *(const f32x4*)(features + nb); gB = *(const f32x4*)(pos_enc + nb);
            }
            { ushort4 pk; pk.x = bf16r(cf2[0]); pk.y = bf16r(cf2[1]);
              pk.z = bf16r(cf2[2]); pk.w = bf16r(cf2[3]); cache[i+1] = pk; }
            dorow(w + 8*(i+1), cf2 + cg2, true);
        }
    }

    // NEG prologue loads issued BEFORE the softmax barrier (stay in flight)
    f32x4 fA, gA, fB, gB;
    {
        size_t aA = rowaddr(POSN + w);
        size_t aB = rowaddr(POSN + w + 8);
        fA = *(const f32x4*)(features + aA); gA = *(const f32x4*)(pos_enc + aA);
        fB = *(const f32x4*)(features + aB); gB = *(const f32x4*)(pos_enc + aB);
    }
    __syncthreads();

    // softmax over p<128 per head (t<256: 32-lane groups), in-place
    if (t < 256) {
        int h = t >> 5, l = t & 31;
        float v0 = affP[l][h], v1 = affP[l+32][h], v2 = affP[l+64][h], v3 = affP[l+96][h];
        float m = fmaxf(fmaxf(v0, v1), fmaxf(v2, v3));
        for (int off = 16; off > 0; off >>= 1) m = fmaxf(m, __shfl_xor(m, off, 32));
        float ex0 = expf(v0 - m), ex1 = expf(v1 - m), ex2 = expf(v2 - m), ex3 = expf(v3 - m);
        float s = ex0 + ex1 + ex2 + ex3;
        for (int off = 16; off > 0; off >>= 1) s += __shfl_xor(s, off, 32);
        float inv = 1.0f / s;
        affP[l][h] = ex0*inv; affP[l+32][h] = ex1*inv; affP[l+64][h] = ex2*inv; affP[l+96][h] = ex3*inv;
    }
    __syncthreads();

    // ============ Phase D: NEG gather interleaved with weighted sum =========
    f32x4 acc[8];
#pragma unroll
    for (int h = 0; h < 8; h++) acc[h] = (f32x4){0.f,0.f,0.f,0.f};
    {
        auto wstep = [&](int i) {
            int p = w + 8*i;
            ushort4 pk = cache[i];
            f32x4 xf;
            xf[0] = bf16f(pk.x); xf[1] = bf16f(pk.y);
            xf[2] = bf16f(pk.z); xf[3] = bf16f(pk.w);
            const f32x4* ap = (const f32x4*)&affP[p][0];
            f32x4 a03 = ap[0], a47 = ap[1];
            acc[0] += xf * a03[0];
            acc[1] += xf * a03[1];
            acc[2] += xf * a03[2];
            acc[3] += xf * a03[3];
            acc[4] += xf * a47[0];
            acc[5] += xf * a47[1];
            acc[6] += xf * a47[2];
            acc[7] += xf * a47[3];
        };
#pragma unroll
        for (int i = 0; i < 16; i += 2) {
            f32x4 cf = fA, cg = gA;
            if (i + 2 < 16) {
                size_t nb = rowaddr(POSN + w + 8*(i+2));
                fA = *(const f32x4*)(features + nb); gA = *(const f32x4*)(pos_enc + nb);
            }
            wstep(i);
            dorow(POSN + w + 8*i, cf + cg, false);
            f32x4 cf2 = fB, cg2 = gB;
            if (i + 3 < 16) {
                size_t nb = rowaddr(POSN + w + 8*(i+3));
                fB = *(const f32x4*)(features + nb); gB = *(const f32x4*)(pos_enc + nb);
            }
            wstep(i+1);
            dorow(POSN + w + 8*(i+1), cf2 + cg2, false);
        }
    }
    // two-batch combine into 32KB of partials
    if (w < 4) {
#pragma unroll
        for (int h = 0; h < 8; h++) wfp[w][h][lane] = acc[h];
    }
    __syncthreads();
    if (w >= 4) {
#pragma unroll
        for (int h = 0; h < 8; h++) wfp[w-4][h][lane] += acc[h];
    }
    __syncthreads();
    {   // combine 4 partials into wf4 (distinct LDS region)
        int h = t >> 6, q2 = t & 63;
        wf4[h][q2] = wfp[0][h][q2] + wfp[1][h][q2] + wfp[2][h][q2] + wfp[3][h][q2];
    }
    __syncthreads();

    // ================= Phase E: projections + residual + LN =================
    {
        int g = t & 255, half = t >> 8;
        const float* vwrow = ipw + (size_t)(2*FEAT + g) * FEAT + half*128;
        const f32x4* wfv = &wf4[g >> 5][half*32];
        float s = 0.f;
#pragma unroll 8
        for (int f4i = 0; f4i < 32; f4i++) {
            f32x4 wv = *(const f32x4*)(vwrow + 4*f4i);
            f32x4 y = wfv[f4i];
            s += wv[0]*y[0] + wv[1]*y[1] + wv[2]*y[2] + wv[3]*y[3];
        }
        aoh[t] = s;
    }
    __syncthreads();
    if (t < 256) ao_l[t] = aoh[t] + aoh[t + 256] + ipb[2*FEAT + t];
    __syncthreads();
    {
        int g = t & 255, half = t >> 8;
        const float* owrow = out_w + (size_t)g * FEAT + half*128;
        const f32x4* av = (const f32x4*)&ao_l[half*128];
        float s = 0.f;
#pragma unroll 8
        for (int f4i = 0; f4i < 32; f4i++) {
            f32x4 wv = *(const f32x4*)(owrow + 4*f4i);
            f32x4 y = av[f4i];
            s += wv[0]*y[0] + wv[1]*y[1] + wv[2]*y[2] + wv[3]*y[3];
        }
        xgh[t] = s;
    }
    __syncthreads();

    float xg = 0.f;
    if (t < 256) {
        xg = xgh[t] + xgh[t + 256] + out_b[t] + slots[n * FEAT + t];
        float s1 = xg, s2 = xg * xg;
        for (int off = 32; off > 0; off >>= 1) {
            s1 += __shfl_xor(s1, off);
            s2 += __shfl_xor(s2, off);
        }
        if ((t & 63) == 0) { rr12[t >> 6] = s1; rr12[4 + (t >> 6)] = s2; }
    }
    __syncthreads();
    if (t < 256) {
        float sum1 = rr12[0] + rr12[1] + rr12[2] + rr12[3];
        float sum2 = rr12[4] + rr12[5] + rr12[6] + rr12[7];
        float mu  = sum1 * (1.0f / FEAT);
        float var = sum2 * (1.0f / FEAT) - mu * mu;
        float nrm = (xg - mu) * rsqrtf(var + LN_EPS);
        out[n * FEAT + t] = nrm * ln_g[t] + ln_b[t];
    }
}

extern "C" void kernel_launch(void* const* d_in, const int* in_sizes, int n_in,
                              void* d_out, int out_size, void* d_ws, size_t ws_size,
                              hipStream_t stream)
{
    (void)in_sizes; (void)n_in; (void)out_size; (void)d_ws; (void)ws_size;
    const float* slots    = (const float*)d_in[0];
    const float* features = (const float*)d_in[1];
    const float* pos_enc  = (const float*)d_in[2];
    const float* curio    = (const float*)d_in[3];
    const int*   batch_idx= (const int*)d_in[4];
    const float* ipw      = (const float*)d_in[5];
    const float* ipb      = (const float*)d_in[6];
    const float* out_w    = (const float*)d_in[7];
    const float* out_b    = (const float*)d_in[8];
    const float* ln_g     = (const float*)d_in[9];
    const float* ln_b     = (const float*)d_in[10];
    const int*   mme      = (const int*)d_in[11];
    float* out = (float*)d_out;
    float* aff = out + AFF_OFF;

    hipLaunchKernelGGL(k_fused, dim3(NSLOT), dim3(512), 0, stream,
                       curio, mme, slots, ipw, ipb, batch_idx, features, pos_enc,
                       out_w, out_b, ln_g, ln_b, aff, out);
}

// Round 14
// 109.539 us; speedup vs baseline: 1.2824x; 1.2824x over previous
//
#include <hip/hip_runtime.h>
#include <hip/hip_bf16.h>

#define FEAT 256
#define HEADS 8
#define HD 32
#define POSN 128
#define NEGN 128
#define HWN 16384
#define BN 8
#define NSLOT 512
#define S_TOT 256
#define LN_EPS 1e-5f
#define NBKT 4096
#define AFF_OFF (NSLOT*FEAT)   /* 131072 floats: new_slots first, then affinities */

typedef float f32x4 __attribute__((ext_vector_type(4)));

__device__ __forceinline__ unsigned short bf16r(float x) {
    unsigned int u = __float_as_uint(x);
    u += 0x7FFFu + ((u >> 16) & 1u);       // round to nearest even
    return (unsigned short)(u >> 16);
}
__device__ __forceinline__ float bf16f(unsigned short h) {
    return __uint_as_float((unsigned int)h << 16);
}

// wave-cooperative 8-row GEMV step: rows Wrows[0..7][FEAT] (row-major, lane
// slice coalesced), x = this lane's 4 elements of the input vector. Returns
// d = full 256-elem dot of row (lane&7); lanes 0..7 hold rows 0..7.
__device__ __forceinline__ float dot8w(const float* __restrict__ Wrows,
                                       f32x4 x, int e0, int e1, int e2, int lane)
{
    const float* p = Wrows + 4 * lane;
    f32x4 w0 = *(const f32x4*)(p + 0*FEAT);
    f32x4 w1 = *(const f32x4*)(p + 1*FEAT);
    f32x4 w2 = *(const f32x4*)(p + 2*FEAT);
    f32x4 w3 = *(const f32x4*)(p + 3*FEAT);
    f32x4 w4 = *(const f32x4*)(p + 4*FEAT);
    f32x4 w5 = *(const f32x4*)(p + 5*FEAT);
    f32x4 w6 = *(const f32x4*)(p + 6*FEAT);
    f32x4 w7 = *(const f32x4*)(p + 7*FEAT);
    float p0 = x[0]*w0[0] + x[1]*w0[1] + x[2]*w0[2] + x[3]*w0[3];
    float p1 = x[0]*w1[0] + x[1]*w1[1] + x[2]*w1[2] + x[3]*w1[3];
    float p2 = x[0]*w2[0] + x[1]*w2[1] + x[2]*w2[2] + x[3]*w2[3];
    float p3 = x[0]*w3[0] + x[1]*w3[1] + x[2]*w3[2] + x[3]*w3[3];
    float p4 = x[0]*w4[0] + x[1]*w4[1] + x[2]*w4[2] + x[3]*w4[3];
    float p5 = x[0]*w5[0] + x[1]*w5[1] + x[2]*w5[2] + x[3]*w5[3];
    float p6 = x[0]*w6[0] + x[1]*w6[1] + x[2]*w6[2] + x[3]*w6[3];
    float p7 = x[0]*w7[0] + x[1]*w7[1] + x[2]*w7[2] + x[3]*w7[3];
    float s0 = e0 ? p0 : p1, s1 = e0 ? p2 : p3, s2 = e0 ? p4 : p5, s3 = e0 ? p6 : p7;
    float a0 = (e0 ? p1 : p0) + __shfl_xor(s0, 1);
    float a1 = (e0 ? p3 : p2) + __shfl_xor(s1, 1);
    float a2 = (e0 ? p5 : p4) + __shfl_xor(s2, 1);
    float a3 = (e0 ? p7 : p6) + __shfl_xor(s3, 1);
    float u0 = e1 ? a0 : a1, u1 = e1 ? a2 : a3;
    float c0 = (e1 ? a1 : a0) + __shfl_xor(u0, 2);
    float c1 = (e1 ? a3 : a2) + __shfl_xor(u1, 2);
    float u2 = e2 ? c0 : c1;
    float d = (e2 ? c1 : c0) + __shfl_xor(u2, 4);
    d += __shfl_xor(d, 8);
    d += __shfl_xor(d, 16);
    d += __shfl_xor(d, 32);
    return d;
}

// ---------------- K1: exact feat_idx sampling + folded qkw -------------------
__global__ __launch_bounds__(256) void k_sample_qkw(const float* __restrict__ curio,
                                                    const int* __restrict__ mme_p,
                                                    const float* __restrict__ slots,
                                                    const float* __restrict__ ipw,
                                                    const float* __restrict__ ipb,
                                                    int* __restrict__ fi_t,
                                                    float* __restrict__ qkw,
                                                    float* __restrict__ qkb)
{
    __shared__ unsigned int hist[NBKT];   // 16KB
    __shared__ uint16_t offs[NBKT];       // 8KB
    __shared__ uint16_t sidx[HWN];        // 32KB
    __shared__ unsigned int ssum[256];    // 1KB
    __shared__ float srow[FEAT];          // 1KB
    __shared__ float qrow[FEAT];          // 1KB
    int slot = blockIdx.x, t = threadIdx.x;
    int lane = t & 63, w = t >> 6;
    const float* cm = curio + (size_t)slot * HWN;
    const f32x4* cm4 = (const f32x4*)cm;

    for (int i = t; i < NBKT; i += 256) hist[i] = 0;
    __syncthreads();

    // pass 1: vectorized stream + histogram; cache bucket ids in registers
    unsigned int bkA[16], bkB[16];
#pragma unroll
    for (int j = 0; j < 16; j++) {
        f32x4 v = cm4[j * 256 + t];
        int b0 = (int)(v[0] * 4096.0f); b0 = b0 < 0 ? 0 : (b0 > NBKT-1 ? NBKT-1 : b0);
        int b1 = (int)(v[1] * 4096.0f); b1 = b1 < 0 ? 0 : (b1 > NBKT-1 ? NBKT-1 : b1);
        int b2 = (int)(v[2] * 4096.0f); b2 = b2 < 0 ? 0 : (b2 > NBKT-1 ? NBKT-1 : b2);
        int b3 = (int)(v[3] * 4096.0f); b3 = b3 < 0 ? 0 : (b3 > NBKT-1 ? NBKT-1 : b3);
        bkA[j] = (unsigned int)b0 | ((unsigned int)b1 << 16);
        bkB[j] = (unsigned int)b2 | ((unsigned int)b3 << 16);
        atomicAdd(&hist[b0], 1u); atomicAdd(&hist[b1], 1u);
        atomicAdd(&hist[b2], 1u); atomicAdd(&hist[b3], 1u);
    }
    __syncthreads();

    // descending-order exclusive prefix: offs[b] = sum_{b'>b} hist[b']
    unsigned int lsum = 0;
    int base = t * 16;
    for (int j = 0; j < 16; j++) lsum += hist[NBKT-1 - (base + j)];
    ssum[t] = lsum; __syncthreads();
    for (int off = 1; off < 256; off <<= 1) {
        unsigned int v = (t >= off) ? ssum[t - off] : 0u;
        __syncthreads();
        ssum[t] += v;
        __syncthreads();
    }
    unsigned int run = ssum[t] - lsum;
    for (int j = 0; j < 16; j++) {
        int b = NBKT-1 - (base + j);
        offs[b] = (uint16_t)run;
        run += hist[b];
    }
    __syncthreads();
    for (int i = t; i < NBKT; i += 256) hist[i] = 0;
    __syncthreads();

    // pass 2: scatter from register-cached buckets (no curio re-read)
#pragma unroll
    for (int j = 0; j < 16; j++) {
        int idx0 = (j * 256 + t) * 4;
        int b0 = (int)(bkA[j] & 0xFFFFu), b1 = (int)(bkA[j] >> 16);
        int b2 = (int)(bkB[j] & 0xFFFFu), b3 = (int)(bkB[j] >> 16);
        unsigned int p0 = (unsigned int)offs[b0] + atomicAdd(&hist[b0], 1u);
        sidx[p0] = (uint16_t)(idx0 + 0);
        unsigned int p1 = (unsigned int)offs[b1] + atomicAdd(&hist[b1], 1u);
        sidx[p1] = (uint16_t)(idx0 + 1);
        unsigned int p2 = (unsigned int)offs[b2] + atomicAdd(&hist[b2], 1u);
        sidx[p2] = (uint16_t)(idx0 + 2);
        unsigned int p3 = (unsigned int)offs[b3] + atomicAdd(&hist[b3], 1u);
        sidx[p3] = (uint16_t)(idx0 + 3);
    }
    __syncthreads();

    // exact rank selection (argsort of -v, stable: value desc, idx asc)
    int mme = mme_p[0];
    int stride = (HWN - POSN - mme) / NEGN;          // 127 for mme=0
    int r = (t < POSN) ? t : (POSN + stride * (t - POSN));
    int lo = 0, hi = NBKT - 1;
    while (lo < hi) { int mid = (lo + hi) >> 1; if ((int)offs[mid] <= r) hi = mid; else lo = mid + 1; }
    int bkt = lo;
    int start = (int)offs[bkt];
    int cnt   = (int)hist[bkt];
    int rr = r - start;
    int besti = sidx[start + (rr < cnt ? rr : 0)];
    for (int j = 0; j < cnt; j++) {
        int ij = sidx[start + j];
        float vj = cm[ij];
        int rank = 0;
        for (int j2 = 0; j2 < cnt; j2++) {
            int i2 = sidx[start + j2];
            float v2 = cm[i2];
            if (v2 > vj || (v2 == vj && i2 < ij)) rank++;
        }
        if (rank == rr) { besti = ij; break; }
    }
    fi_t[slot * S_TOT + t] = besti;   // fi_t[n][s]

    // ---- folded qkw for this slot (q via coalesced butterfly GEMV) ----
    __syncthreads();
    srow[t] = slots[slot * FEAT + t];
    __syncthreads();
    {
        int e0 = lane & 1, e1 = (lane >> 1) & 1, e2 = (lane >> 2) & 1;
        f32x4 xs = *(const f32x4*)&srow[4 * lane];
        const float scaling = 0.17677669529663687f;     // 32^-0.5
#pragma unroll
        for (int c = 0; c < 8; c++) {
            int r0 = w * 64 + c * 8;
            float d = dot8w(ipw + (size_t)r0 * FEAT, xs, e0, e1, e2, lane);
            if (lane < 8) qrow[r0 + lane] = (d + ipb[r0 + lane]) * scaling;
        }
    }
    __syncthreads();
    if (t < HEADS) {
        float s = 0.f;
        for (int d = 0; d < HD; d++) s += qrow[t*HD + d] * ipb[FEAT + t*HD + d];
        qkb[slot * HEADS + t] = s;
    }
    const float* kw = ipw + FEAT * FEAT;
    for (int e = t; e < HEADS * FEAT; e += 256) {
        int h = e >> 8, f = e & 255;
        float s = 0.f;
#pragma unroll
        for (int d = 0; d < HD; d++) s += qrow[h*HD + d] * kw[(h*HD + d) * FEAT + f];
        qkw[(size_t)slot * (HEADS*FEAT) + e] = s;
    }
}

// ---------------- K2: gather + aff + softmax + wsum + coalesced proj + LN ----
// R12's memory kernel with the projection epilogue merged back, now using
// wave-cooperative butterfly-8 GEMVs (coalesced 1KB weight-row loads) instead
// of per-thread strided rows. Wave w owns head w's 32 V-rows and O-rows.
__global__ __launch_bounds__(512) void k_attn(const float* __restrict__ features,
                                              const float* __restrict__ pos_enc,
                                              const int* __restrict__ batch_idx,
                                              const int* __restrict__ fi_t,
                                              const float* __restrict__ qkw,
                                              const float* __restrict__ qkb,
                                              const float* __restrict__ slots,
                                              const float* __restrict__ ipw,
                                              const float* __restrict__ ipb,
                                              const float* __restrict__ out_w,
                                              const float* __restrict__ out_b,
                                              const float* __restrict__ ln_g,
                                              const float* __restrict__ ln_b,
                                              float* __restrict__ aff_out,
                                              float* __restrict__ out)
{
    __shared__ int   fi_l[S_TOT];                      // 1KB
    __shared__ float qkb_l[HEADS];
    __shared__ __align__(16) float affP[POSN][8];      // 4KB: aff then attn
    __shared__ f32x4 wfp[4][HEADS][64];                // 32KB partials; wfp[0]=wf
    __shared__ __align__(16) float ao_l[FEAT];         // 1KB
    __shared__ float xgh[FEAT];                        // 1KB
    __shared__ float rr12[8];

    int n = blockIdx.x, t = threadIdx.x, lane = t & 63, w = t >> 6;
    if (t < S_TOT) fi_l[t] = fi_t[n * S_TOT + t];
    if (t < HEADS) qkb_l[t] = qkb[n * HEADS + t];
    int b = batch_idx[n];

    const float* qk = qkw + (size_t)n * (HEADS*FEAT) + 4 * lane;
    f32x4 qw0 = *(const f32x4*)(qk + 0*FEAT);
    f32x4 qw1 = *(const f32x4*)(qk + 1*FEAT);
    f32x4 qw2 = *(const f32x4*)(qk + 2*FEAT);
    f32x4 qw3 = *(const f32x4*)(qk + 3*FEAT);
    f32x4 qw4 = *(const f32x4*)(qk + 4*FEAT);
    f32x4 qw5 = *(const f32x4*)(qk + 5*FEAT);
    f32x4 qw6 = *(const f32x4*)(qk + 6*FEAT);
    f32x4 qw7 = *(const f32x4*)(qk + 7*FEAT);
    __syncthreads();
    float qb = qkb_l[lane & 7];
    int e0 = lane & 1, e1 = (lane >> 1) & 1, e2 = (lane >> 2) & 1;

    auto dorow = [&](int p, f32x4 x, bool toLds) {
        float p0 = x[0]*qw0[0] + x[1]*qw0[1] + x[2]*qw0[2] + x[3]*qw0[3];
        float p1 = x[0]*qw1[0] + x[1]*qw1[1] + x[2]*qw1[2] + x[3]*qw1[3];
        float p2 = x[0]*qw2[0] + x[1]*qw2[1] + x[2]*qw2[2] + x[3]*qw2[3];
        float p3 = x[0]*qw3[0] + x[1]*qw3[1] + x[2]*qw3[2] + x[3]*qw3[3];
        float p4 = x[0]*qw4[0] + x[1]*qw4[1] + x[2]*qw4[2] + x[3]*qw4[3];
        float p5 = x[0]*qw5[0] + x[1]*qw5[1] + x[2]*qw5[2] + x[3]*qw5[3];
        float p6 = x[0]*qw6[0] + x[1]*qw6[1] + x[2]*qw6[2] + x[3]*qw6[3];
        float p7 = x[0]*qw7[0] + x[1]*qw7[1] + x[2]*qw7[2] + x[3]*qw7[3];
        float s0 = e0 ? p0 : p1, s1 = e0 ? p2 : p3, s2 = e0 ? p4 : p5, s3 = e0 ? p6 : p7;
        float a0 = (e0 ? p1 : p0) + __shfl_xor(s0, 1);
        float a1 = (e0 ? p3 : p2) + __shfl_xor(s1, 1);
        float a2 = (e0 ? p5 : p4) + __shfl_xor(s2, 1);
        float a3 = (e0 ? p7 : p6) + __shfl_xor(s3, 1);
        float u0 = e1 ? a0 : a1, u1 = e1 ? a2 : a3;
        float c0 = (e1 ? a1 : a0) + __shfl_xor(u0, 2);
        float c1 = (e1 ? a3 : a2) + __shfl_xor(u1, 2);
        float u2 = e2 ? c0 : c1;
        float d = (e2 ? c1 : c0) + __shfl_xor(u2, 4);
        d += __shfl_xor(d, 8);
        d += __shfl_xor(d, 16);
        d += __shfl_xor(d, 32);
        d += qb;
        if (lane < 8) {
            aff_out[(size_t)p * (NSLOT*HEADS) + n*HEADS + lane] = d;
            if (toLds) affP[p][lane] = d;
        }
    };

    auto rowaddr = [&](int s) {
        return ((size_t)fi_l[s] * BN + b) * FEAT + 4 * lane;
    };

    // ---- Phase B: POS rows p = w + 8i, bf16 cache, depth-2 prefetch ----
    ushort4 cache[16];
    {
        size_t aA = rowaddr(w);
        size_t aB = rowaddr(w + 8);
        f32x4 fA = *(const f32x4*)(features + aA), gA = *(const f32x4*)(pos_enc + aA);
        f32x4 fB = *(const f32x4*)(features + aB), gB = *(const f32x4*)(pos_enc + aB);
#pragma unroll
        for (int i = 0; i < 16; i += 2) {
            f32x4 cf = fA, cg = gA;
            if (i + 2 < 16) {
                size_t nb = rowaddr(w + 8*(i+2));
                fA = *(const f32x4*)(features + nb); gA = *(const f32x4*)(pos_enc + nb);
            }
            { ushort4 pk; pk.x = bf16r(cf[0]); pk.y = bf16r(cf[1]);
              pk.z = bf16r(cf[2]); pk.w = bf16r(cf[3]); cache[i] = pk; }
            dorow(w + 8*i, cf + cg, true);
            f32x4 cf2 = fB, cg2 = gB;
            if (i + 3 < 16) {
                size_t nb = rowaddr(w + 8*(i+3));
                fB = *(const f32x4*)(features + nb); gB = *(const f32x4*)(pos_enc + nb);
            }
            { ushort4 pk; pk.x = bf16r(cf2[0]); pk.y = bf16r(cf2[1]);
              pk.z = bf16r(cf2[2]); pk.w = bf16r(cf2[3]); cache[i+1] = pk; }
            dorow(w + 8*(i+1), cf2 + cg2, true);
        }
    }

    // NEG prologue loads issued BEFORE the softmax barrier (stay in flight)
    f32x4 fA, gA, fB, gB;
    {
        size_t aA = rowaddr(POSN + w);
        size_t aB = rowaddr(POSN + w + 8);
        fA = *(const f32x4*)(features + aA); gA = *(const f32x4*)(pos_enc + aA);
        fB = *(const f32x4*)(features + aB); gB = *(const f32x4*)(pos_enc + aB);
    }
    __syncthreads();

    // ---- softmax over p<128 per head (t<256: 32-lane groups), in-place ----
    if (t < 256) {
        int h = t >> 5, l = t & 31;
        float v0 = affP[l][h], v1 = affP[l+32][h], v2 = affP[l+64][h], v3 = affP[l+96][h];
        float m = fmaxf(fmaxf(v0, v1), fmaxf(v2, v3));
        for (int off = 16; off > 0; off >>= 1) m = fmaxf(m, __shfl_xor(m, off, 32));
        float ex0 = expf(v0 - m), ex1 = expf(v1 - m), ex2 = expf(v2 - m), ex3 = expf(v3 - m);
        float s = ex0 + ex1 + ex2 + ex3;
        for (int off = 16; off > 0; off >>= 1) s += __shfl_xor(s, off, 32);
        float inv = 1.0f / s;
        affP[l][h] = ex0*inv; affP[l+32][h] = ex1*inv; affP[l+64][h] = ex2*inv; affP[l+96][h] = ex3*inv;
    }
    __syncthreads();

    // ---- Phase C: NEG gather (depth-2) interleaved with weighted sum -------
    f32x4 acc[8];
#pragma unroll
    for (int h = 0; h < 8; h++) acc[h] = (f32x4){0.f,0.f,0.f,0.f};
    {
        auto wstep = [&](int i) {
            int p = w + 8*i;
            ushort4 pk = cache[i];
            f32x4 xf;
            xf[0] = bf16f(pk.x); xf[1] = bf16f(pk.y);
            xf[2] = bf16f(pk.z); xf[3] = bf16f(pk.w);
            const f32x4* ap = (const f32x4*)&affP[p][0];
            f32x4 a03 = ap[0], a47 = ap[1];
            acc[0] += xf * a03[0];
            acc[1] += xf * a03[1];
            acc[2] += xf * a03[2];
            acc[3] += xf * a03[3];
            acc[4] += xf * a47[0];
            acc[5] += xf * a47[1];
            acc[6] += xf * a47[2];
            acc[7] += xf * a47[3];
        };
#pragma unroll
        for (int i = 0; i < 16; i += 2) {
            f32x4 cf = fA, cg = gA;
            if (i + 2 < 16) {
                size_t nb = rowaddr(POSN + w + 8*(i+2));
                fA = *(const f32x4*)(features + nb); gA = *(const f32x4*)(pos_enc + nb);
            }
            wstep(i);
            dorow(POSN + w + 8*i, cf + cg, false);
            f32x4 cf2 = fB, cg2 = gB;
            if (i + 3 < 16) {
                size_t nb = rowaddr(POSN + w + 8*(i+3));
                fB = *(const f32x4*)(features + nb); gB = *(const f32x4*)(pos_enc + nb);
            }
            wstep(i+1);
            dorow(POSN + w + 8*(i+1), cf2 + cg2, false);
        }
    }
    // two-batch combine into 32KB of partials; final wf lands in wfp[0]
    if (w < 4) {
#pragma unroll
        for (int h = 0; h < 8; h++) wfp[w][h][lane] = acc[h];
    }
    __syncthreads();
    if (w >= 4) {
#pragma unroll
        for (int h = 0; h < 8; h++) wfp[w-4][h][lane] += acc[h];
    }
    __syncthreads();
    {   // combine 4 partials in-place into wfp[0] (one (h,q) per thread)
        int h = t >> 6, q2 = t & 63;
        f32x4 s = wfp[0][h][q2] + wfp[1][h][q2] + wfp[2][h][q2] + wfp[3][h][q2];
        wfp[0][h][q2] = s;
    }
    __syncthreads();

    // ---- V-projection: wave w owns head w's 32 rows (butterfly-8 GEMV) -----
    {
        const float* vw = ipw + (size_t)(2*FEAT) * FEAT;
        f32x4 xv = wfp[0][w][lane];
#pragma unroll
        for (int c = 0; c < 4; c++) {
            int r0 = w * 32 + c * 8;
            float d = dot8w(vw + (size_t)r0 * FEAT, xv, e0, e1, e2, lane);
            if (lane < 8) ao_l[r0 + lane] = d + ipb[2*FEAT + r0 + lane];
        }
    }
    __syncthreads();

    // ---- out-projection: same pattern over out_w ----------------------------
    {
        f32x4 xo = *(const f32x4*)&ao_l[4 * lane];
#pragma unroll
        for (int c = 0; c < 4; c++) {
            int r0 = w * 32 + c * 8;
            float d = dot8w(out_w + (size_t)r0 * FEAT, xo, e0, e1, e2, lane);
            if (lane < 8) xgh[r0 + lane] = d;
        }
    }
    __syncthreads();

    // ---- residual + LayerNorm ----------------------------------------------
    float xg = 0.f;
    if (t < 256) {
        xg = xgh[t] + out_b[t] + slots[n * FEAT + t];
        float s1 = xg, s2 = xg * xg;
        for (int off = 32; off > 0; off >>= 1) {
            s1 += __shfl_xor(s1, off);
            s2 += __shfl_xor(s2, off);
        }
        if ((t & 63) == 0) { rr12[t >> 6] = s1; rr12[4 + (t >> 6)] = s2; }
    }
    __syncthreads();
    if (t < 256) {
        float sum1 = rr12[0] + rr12[1] + rr12[2] + rr12[3];
        float sum2 = rr12[4] + rr12[5] + rr12[6] + rr12[7];
        float mu  = sum1 * (1.0f / FEAT);
        float var = sum2 * (1.0f / FEAT) - mu * mu;
        float nrm = (xg - mu) * rsqrtf(var + LN_EPS);
        out[n * FEAT + t] = nrm * ln_g[t] + ln_b[t];
    }
}

extern "C" void kernel_launch(void* const* d_in, const int* in_sizes, int n_in,
                              void* d_out, int out_size, void* d_ws, size_t ws_size,
                              hipStream_t stream)
{
    (void)in_sizes; (void)n_in; (void)out_size; (void)ws_size;
    const float* slots    = (const float*)d_in[0];
    const float* features = (const float*)d_in[1];
    const float* pos_enc  = (const float*)d_in[2];
    const float* curio    = (const float*)d_in[3];
    const int*   batch_idx= (const int*)d_in[4];
    const float* ipw      = (const float*)d_in[5];
    const float* ipb      = (const float*)d_in[6];
    const float* out_w    = (const float*)d_in[7];
    const float* out_b    = (const float*)d_in[8];
    const float* ln_g     = (const float*)d_in[9];
    const float* ln_b     = (const float*)d_in[10];
    const int*   mme      = (const int*)d_in[11];
    float* out = (float*)d_out;

    char* ws = (char*)d_ws;
    int*   fi_t = (int*)ws;                                 // 512*256*4 = 512KB
    float* qkw  = (float*)(ws + (512 << 10));               // 512*2048*4 = 4MB
    float* qkb  = (float*)(ws + (512 << 10) + (4 << 20));   // 16KB
    float* aff  = out + AFF_OFF;

    hipLaunchKernelGGL(k_sample_qkw, dim3(NSLOT), dim3(256), 0, stream,
                       curio, mme, slots, ipw, ipb, fi_t, qkw, qkb);
    hipLaunchKernelGGL(k_attn, dim3(NSLOT), dim3(512), 0, stream,
                       features, pos_enc, batch_idx, fi_t, qkw, qkb, slots, ipw, ipb,
                       out_w, out_b, ln_g, ln_b, aff, out);
}